// Round 6
// baseline (1086.810 us; speedup 1.0000x reference)
//
#include <hip/hip_runtime.h>
#include <math.h>

// PLRNN forward via MFMA matvec. 256 batches x 1024 steps, 1 WG (512 thr,
// 8 waves) per batch, 1 per CU. Weights resident as f16 MFMA A-fragments.
// Per step (2 barriers):
//   p1 (M-split): wave w -> pre rows [64w,64w+64): 4x4 MFMA, acc init = h2.
//   bounce (wave-local): relu+f16, col-spread write of r[64w..64w+64).
//   p2 (K-split): wave w -> partial u[0..127] over k in [64w,64w+64): 8x2 MFMA.
//       wave 0 adds tail K-tile (k=512..543): [C | h1 | 0] x [s~ | 1 | 0].
//   partial: col-spread write part[w][0..127] (1 op). B1.
//   reduce: 1 vector read (lane l: ww=l&7, zb=(l>>3)&3) + xor1/xor2 DPP +
//       xor4 ds_swizzle -> u final in-register, duplicated.
//   update (all waves, rows [16w,16w+16)): znew = A*zf + u; TF via Xc; 4
//       writer lanes publish zf_h (f16) + outc. B2.
// X/S/out staged in LDS per 128-step chunk -> no global ops in steady state.

#define NB 256
#define T  1024
#define DX 64
#define DZ 128
#define DH 512
#define DS 16
#define CHUNK 128

typedef _Float16 half8 __attribute__((ext_vector_type(8)));
typedef _Float16 v4h   __attribute__((ext_vector_type(4)));
typedef float    f32x4 __attribute__((ext_vector_type(4)));

__device__ __forceinline__ half8 cvt8(const float* __restrict__ src) {
  const float4 a = *reinterpret_cast<const float4*>(src);
  const float4 c = *reinterpret_cast<const float4*>(src + 4);
  half8 h;
  h[0] = (_Float16)a.x; h[1] = (_Float16)a.y; h[2] = (_Float16)a.z; h[3] = (_Float16)a.w;
  h[4] = (_Float16)c.x; h[5] = (_Float16)c.y; h[6] = (_Float16)c.z; h[7] = (_Float16)c.w;
  return h;
}

__device__ __forceinline__ f32x4 sel4(int c, f32x4 a, f32x4 b) {   // c ? a : b
  f32x4 r;
  r[0] = c ? a[0] : b[0];  r[1] = c ? a[1] : b[1];
  r[2] = c ? a[2] : b[2];  r[3] = c ? a[3] : b[3];
  return r;
}

template <int CTRL>
__device__ __forceinline__ f32x4 dpp_xor_add(f32x4 v) {            // v += v[lane^d] (quad)
  f32x4 r;
  #pragma unroll
  for (int j = 0; j < 4; ++j) {
    const int t = __builtin_amdgcn_update_dpp(0, __float_as_int(v[j]), CTRL, 0xF, 0xF, true);
    r[j] = v[j] + __int_as_float(t);
  }
  return r;
}

__device__ __forceinline__ f32x4 swz_xor4_add(f32x4 v) {           // v += v[lane^4]
  f32x4 r;
  #pragma unroll
  for (int j = 0; j < 4; ++j) {
    const int t = __builtin_amdgcn_ds_swizzle(__float_as_int(v[j]), 0x101F);
    r[j] = v[j] + __int_as_float(t);
  }
  return r;
}

__global__ __launch_bounds__(512, 2) void plrnn_kernel(
    const float* __restrict__ X, const float* __restrict__ S,
    const float* __restrict__ A, const float* __restrict__ W1,
    const float* __restrict__ W2, const float* __restrict__ h1,
    const float* __restrict__ h2, const float* __restrict__ C,
    float* __restrict__ out)
{
  __shared__ __align__(16) _Float16 zf_h[DZ];          // 256 B
  __shared__ __align__(16) _Float16 rt[544];           // r(512) + s~(16) + [1,0..](16)
  __shared__ __align__(16) float    part[8][132];      // padded: bank-spread
  __shared__ __align__(16) float    Xc[CHUNK][DX];     // 32 KiB: X[t+1 .. t+128]
  __shared__ __align__(16) float    Sc[CHUNK][DS];     // 8 KiB:  S[t .. t+127]
  __shared__ __align__(16) float    outc[CHUNK][DX];   // 32 KiB

  const int b   = blockIdx.x;
  const int tid = threadIdx.x;
  const int w   = tid >> 6;            // wave 0..7
  const int l   = tid & 63;
  const int g   = l >> 4;              // 16-lane group (B k-slice / D row-block)
  const int r15 = l & 15;              // A row-in-tile / D col
  const int zb  = (l >> 3) & 3;        // reduce/update row-block within wave slice

  // ---- one-time: stage chunk 0 (X rows 1..128 clamped, S rows 0..127) ----
  {
    #pragma unroll
    for (int k = 0; k < 4; ++k) {
      const int flat = k * 2048 + tid * 4;
      int srow = 1 + (flat >> 6);
      if (srow > T - 1) srow = T - 1;
      const float4 v = *reinterpret_cast<const float4*>(X + ((size_t)b * T + srow) * DX + (flat & 63));
      *reinterpret_cast<float4*>(&((float*)Xc)[flat]) = v;
    }
    const int flat = tid * 4;
    const float4 v = *reinterpret_cast<const float4*>(S + ((size_t)b * T) * DS + flat);
    *reinterpret_cast<float4*>(&((float*)Sc)[flat]) = v;
  }

  // ---- one-time: rt constant tail [528..543] = [1, 0...0] (wave-0 local) ----
  if (tid < 16) rt[528 + tid] = (tid == 0) ? (_Float16)1.0f : (_Float16)0.0f;

  // ---- one-time: W2 A-fragments (wave w: rows 64w+16mt+r15, k=32kt+8g+e) ----
  half8 w2f[4][4];
  #pragma unroll
  for (int mt = 0; mt < 4; ++mt)
    #pragma unroll
    for (int kt = 0; kt < 4; ++kt)
      w2f[mt][kt] = cvt8(W2 + ((size_t)b * DH + 64 * w + 16 * mt + r15) * DZ + 32 * kt + 8 * g);

  // ---- one-time: W1 A-fragments (rows 16mt+r15, k=64w+32kt+8g+e) ----
  half8 w1f[8][2];
  #pragma unroll
  for (int mt = 0; mt < 8; ++mt)
    #pragma unroll
    for (int kt = 0; kt < 2; ++kt)
      w1f[mt][kt] = cvt8(W1 + ((size_t)b * DZ + 16 * mt + r15) * DH + 64 * w + 32 * kt + 8 * g);

  // ---- one-time: wave-0 tail fragments (k=512+8g+e): [C | h1 | 0] ----
  half8 w1ft[8];
  #pragma unroll
  for (int mt = 0; mt < 8; ++mt)
    #pragma unroll
    for (int e = 0; e < 8; ++e) w1ft[mt][e] = (_Float16)0.0f;
  if (w == 0) {
    #pragma unroll
    for (int mt = 0; mt < 8; ++mt) {
      const int row = 16 * mt + r15;
      if (g == 0)      w1ft[mt] = cvt8(C + ((size_t)b * DZ + row) * DS + 0);
      else if (g == 1) w1ft[mt] = cvt8(C + ((size_t)b * DZ + row) * DS + 8);
      else if (g == 2) w1ft[mt][0] = (_Float16)h1[(size_t)b * DZ + row];
    }
  }

  // ---- one-time: h2 as acc-init (D rows 4g+j of each mt) ----
  f32x4 h2v[4];
  #pragma unroll
  for (int mt = 0; mt < 4; ++mt)
    h2v[mt] = *reinterpret_cast<const f32x4*>(h2 + (size_t)b * DH + 64 * w + 16 * mt + 4 * g);

  // ---- one-time: update constants (rows 16w+4zb+j, duplicated x16) ----
  const f32x4 Areg = *reinterpret_cast<const f32x4*>(A + (size_t)b * DZ + 16 * w + 4 * zb);
  f32x4 zfcur = {0.f, 0.f, 0.f, 0.f};
  if (w < 4) {
    const f32x4 x0 = *reinterpret_cast<const f32x4*>(X + ((size_t)b * T) * DX + 16 * w + 4 * zb);
    #pragma unroll
    for (int j = 0; j < 4; ++j) zfcur[j] = (x0[j] != x0[j]) ? 0.f : x0[j];  // TF(0,X0,1)+TF = x
  }
  if (l < 32 && (l & 7) == 0) {        // 4 writer lanes per wave: one per zb
    v4h zp;
    #pragma unroll
    for (int j = 0; j < 4; ++j) zp[j] = (_Float16)zfcur[j];
    *reinterpret_cast<v4h*>(&zf_h[16 * w + 4 * zb]) = zp;
  }
  __syncthreads();

  const f32x4 zero4 = {0.f, 0.f, 0.f, 0.f};

  for (int t = 0; t < T; ++t) {
    // ---- chunk boundary: flush out-chunk, stage next X/S chunk ----
    if ((t & (CHUNK - 1)) == 0 && t) {
      const int c0 = t - CHUNK;
      #pragma unroll
      for (int k = 0; k < 4; ++k) {
        const int flat = k * 2048 + tid * 4;
        const float4 v = *reinterpret_cast<const float4*>(&((float*)outc)[flat]);
        *reinterpret_cast<float4*>(out + ((size_t)b * T + c0) * DX + flat) = v;
      }
      #pragma unroll
      for (int k = 0; k < 4; ++k) {
        const int flat = k * 2048 + tid * 4;
        int srow = t + 1 + (flat >> 6);
        if (srow > T - 1) srow = T - 1;
        const float4 v = *reinterpret_cast<const float4*>(X + ((size_t)b * T + srow) * DX + (flat & 63));
        *reinterpret_cast<float4*>(&((float*)Xc)[flat]) = v;
      }
      const int flat = tid * 4;
      const float4 v = *reinterpret_cast<const float4*>(S + ((size_t)b * T + t) * DS + flat);
      *reinterpret_cast<float4*>(&((float*)Sc)[flat]) = v;
      __syncthreads();
    }
    const int tc = t & (CHUNK - 1);

    // ---- s~ staging for this step (wave-0 local, overlaps p1) ----
    if (w == 0 && l < 4) {
      const f32x4 sv = *reinterpret_cast<const f32x4*>(&Sc[tc][4 * l]);
      v4h sp;
      #pragma unroll
      for (int j = 0; j < 4; ++j) sp[j] = (_Float16)sv[j];
      *reinterpret_cast<v4h*>(&rt[512 + 4 * l]) = sp;
    }

    // ---- phase 1: pre = h2 + W2·zf (16 MFMA) ----
    half8 bz[4];
    #pragma unroll
    for (int kt = 0; kt < 4; ++kt)
      bz[kt] = *reinterpret_cast<const half8*>(zf_h + 32 * kt + 8 * g);

    f32x4 acc1[4];
    #pragma unroll
    for (int mt = 0; mt < 4; ++mt)
      acc1[mt] = __builtin_amdgcn_mfma_f32_16x16x32_f16(w2f[mt][0], bz[0], h2v[mt], 0, 0, 0);
    #pragma unroll
    for (int kt = 1; kt < 4; ++kt)
      #pragma unroll
      for (int mt = 0; mt < 4; ++mt)
        acc1[mt] = __builtin_amdgcn_mfma_f32_16x16x32_f16(w2f[mt][kt], bz[kt], acc1[mt], 0, 0, 0);

    // ---- bounce (wave-local): col-spread relu+f16 write of r[64w..64w+64) ----
    {
      const f32x4 lo = sel4(r15 & 1, acc1[1], acc1[0]);
      const f32x4 hi = sel4(r15 & 1, acc1[3], acc1[2]);
      const f32x4 sv = sel4(r15 & 2, hi, lo);
      if (r15 < 4) {
        v4h p;
        #pragma unroll
        for (int j = 0; j < 4; ++j) p[j] = (_Float16)fmaxf(sv[j], 0.f);
        *reinterpret_cast<v4h*>(&rt[64 * w + 16 * r15 + 4 * g]) = p;
      }
    }

    // ---- phase 2: partial u over k=[64w,64w+64) (16 MFMA; wave 0: +8 tail) ----
    half8 br[2];
    #pragma unroll
    for (int kt = 0; kt < 2; ++kt)
      br[kt] = *reinterpret_cast<const half8*>(rt + 64 * w + 32 * kt + 8 * g);

    f32x4 acc2[8];
    #pragma unroll
    for (int mt = 0; mt < 8; ++mt)
      acc2[mt] = __builtin_amdgcn_mfma_f32_16x16x32_f16(w1f[mt][0], br[0], zero4, 0, 0, 0);
    #pragma unroll
    for (int mt = 0; mt < 8; ++mt)
      acc2[mt] = __builtin_amdgcn_mfma_f32_16x16x32_f16(w1f[mt][1], br[1], acc2[mt], 0, 0, 0);
    if (w == 0) {
      const half8 brt = *reinterpret_cast<const half8*>(rt + 512 + 8 * g);
      #pragma unroll
      for (int mt = 0; mt < 8; ++mt)
        acc2[mt] = __builtin_amdgcn_mfma_f32_16x16x32_f16(w1ft[mt], brt, acc2[mt], 0, 0, 0);
    }

    // ---- col-spread partial write: part[w][16(c)+4g+j] from acc2[c], c=r15<8 ----
    {
      const f32x4 s01 = sel4(r15 & 1, acc2[1], acc2[0]);
      const f32x4 s23 = sel4(r15 & 1, acc2[3], acc2[2]);
      const f32x4 s45 = sel4(r15 & 1, acc2[5], acc2[4]);
      const f32x4 s67 = sel4(r15 & 1, acc2[7], acc2[6]);
      const f32x4 a03 = sel4(r15 & 2, s23, s01);
      const f32x4 a47 = sel4(r15 & 2, s67, s45);
      const f32x4 sv  = sel4(r15 & 4, a47, a03);
      if (r15 < 8)
        *reinterpret_cast<f32x4*>(&part[w][16 * r15 + 4 * g]) = sv;
    }
    __syncthreads();   // B1: partials visible

    // ---- reduce: lane l reads part[l&7][16w+4zb]; xor1,xor2 (DPP) + xor4 (swz) ----
    f32x4 u = *reinterpret_cast<const f32x4*>(&part[l & 7][16 * w + 4 * zb]);
    u = dpp_xor_add<0xB1>(u);          // quad_perm(1,0,3,2): lane^1
    u = dpp_xor_add<0x4E>(u);          // quad_perm(2,3,0,1): lane^2
    u = swz_xor4_add(u);               // ds_swizzle xor 4

    // ---- distributed update: rows 16w+4zb+j (all lanes, dup x16) ----
    f32x4 zn, zfn;
    #pragma unroll
    for (int j = 0; j < 4; ++j) zn[j] = Areg[j] * zfcur[j] + u[j];
    zfn = zn;
    if (w < 4) {
      const f32x4 xv = *reinterpret_cast<const f32x4*>(&Xc[tc][16 * w + 4 * zb]);
      #pragma unroll
      for (int j = 0; j < 4; ++j)
        zfn[j] = (xv[j] != xv[j]) ? zn[j] : (0.125f * xv[j] + 0.875f * zn[j]);
      if (l < 32 && (l & 7) == 0)
        *reinterpret_cast<f32x4*>(&outc[tc][16 * w + 4 * zb]) = zn;
    }
    zfcur = zfn;
    if (l < 32 && (l & 7) == 0) {
      v4h zp;
      #pragma unroll
      for (int j = 0; j < 4; ++j) zp[j] = (_Float16)zfn[j];
      *reinterpret_cast<v4h*>(&zf_h[16 * w + 4 * zb]) = zp;
    }
    __syncthreads();   // B2: zf(t+1) visible
  }

  // ---- final flush (last chunk) ----
  {
    const int c0 = T - CHUNK;
    #pragma unroll
    for (int k = 0; k < 4; ++k) {
      const int flat = k * 2048 + tid * 4;
      const float4 v = *reinterpret_cast<const float4*>(&((float*)outc)[flat]);
      *reinterpret_cast<float4*>(out + ((size_t)b * T + c0) * DX + flat) = v;
    }
  }
}

extern "C" void kernel_launch(void* const* d_in, const int* in_sizes, int n_in,
                              void* d_out, int out_size, void* d_ws, size_t ws_size,
                              hipStream_t stream) {
  const float* X  = (const float*)d_in[0];
  const float* S  = (const float*)d_in[1];
  const float* A  = (const float*)d_in[2];
  const float* W1 = (const float*)d_in[3];
  const float* W2 = (const float*)d_in[4];
  const float* h1 = (const float*)d_in[5];
  const float* h2 = (const float*)d_in[6];
  const float* C  = (const float*)d_in[7];
  float* out = (float*)d_out;
  plrnn_kernel<<<dim3(NB), dim3(512), 0, stream>>>(X, S, A, W1, W2, h1, h2, C, out);
}